// Round 1
// baseline (123.352 us; speedup 1.0000x reference)
//
#include <hip/hip_runtime.h>

#define SQ1_2 0.70710678118654752440f

// Feature in log2 domain: g2(x) = sign(x) * log2(1+|x|).
// Reference uses ln; (g_ln(a)-g_ln(b))^2 = ln2^2 * (g2(a)-g2(b))^2,
// so ln2^2 is folded into the final scale. Saves one v_mul per feature.
__device__ __forceinline__ float g2f(float x) {
    return copysignf(__log2f(1.0f + fabsf(x)), x);
}

// Real 8-point DFT. Input r[0..7]; output packed:
// o[0]=F0 (real), o[1]=F4 (real), o[2..3]=F1 (re,im), o[4..5]=F2, o[6..7]=F3.
__device__ __forceinline__ void rfft8(const float r[8], float o[8]) {
    float s0 = r[0] + r[4], d0 = r[0] - r[4];
    float s1 = r[1] + r[5], d1 = r[1] - r[5];
    float s2 = r[2] + r[6], d2 = r[2] - r[6];
    float s3 = r[3] + r[7], d3 = r[3] - r[7];
    float ss02 = s0 + s2, sd02 = s0 - s2;
    float ss13 = s1 + s3, sd13 = s1 - s3;
    float t1 = SQ1_2 * (d1 - d3);
    float t2 = SQ1_2 * (d1 + d3);
    o[0] = ss02 + ss13;       // F0
    o[1] = ss02 - ss13;       // F4
    o[2] = d0 + t1;           // F1r
    o[3] = -(d2 + t2);        // F1i
    o[4] = sd02;              // F2r
    o[5] = -sd13;             // F2i
    o[6] = d0 - t1;           // F3r
    o[7] = d2 - t2;           // F3i
}

// Complex 8-point DFT (DIT radix-2): inputs xr/xi[8], outputs Fr/Fi[8].
__device__ __forceinline__ void cfft8(const float xr[8], const float xi[8],
                                      float Fr[8], float Fi[8]) {
    float s0r = xr[0] + xr[4], s0i = xi[0] + xi[4], d0r = xr[0] - xr[4], d0i = xi[0] - xi[4];
    float s1r = xr[1] + xr[5], s1i = xi[1] + xi[5], d1r = xr[1] - xr[5], d1i = xi[1] - xi[5];
    float s2r = xr[2] + xr[6], s2i = xi[2] + xi[6], d2r = xr[2] - xr[6], d2i = xi[2] - xi[6];
    float s3r = xr[3] + xr[7], s3i = xi[3] + xi[7], d3r = xr[3] - xr[7], d3i = xi[3] - xi[7];
    // even half: DFT4 of s
    float ss0r = s0r + s2r, ss0i = s0i + s2i, sd0r = s0r - s2r, sd0i = s0i - s2i;
    float ss1r = s1r + s3r, ss1i = s1i + s3i, sd1r = s1r - s3r, sd1i = s1i - s3i;
    Fr[0] = ss0r + ss1r; Fi[0] = ss0i + ss1i;
    Fr[4] = ss0r - ss1r; Fi[4] = ss0i - ss1i;
    Fr[2] = sd0r + sd1i; Fi[2] = sd0i - sd1r;   // sd0 - i*sd1
    Fr[6] = sd0r - sd1i; Fi[6] = sd0i + sd1r;   // sd0 + i*sd1
    // odd half: twiddle then DFT4
    float t1r = SQ1_2 * (d1r + d1i), t1i = SQ1_2 * (d1i - d1r);   // d1 * e^{-i pi/4}
    float t2r = d2i,                 t2i = -d2r;                  // d2 * (-i)
    float t3r = SQ1_2 * (d3i - d3r), t3i = -SQ1_2 * (d3r + d3i);  // d3 * e^{-i 3pi/4}
    float ts0r = d0r + t2r, ts0i = d0i + t2i, td0r = d0r - t2r, td0i = d0i - t2i;
    float ts1r = t1r + t3r, ts1i = t1i + t3i, td1r = t1r - t3r, td1i = t1i - t3i;
    Fr[1] = ts0r + ts1r; Fi[1] = ts0i + ts1i;
    Fr[5] = ts0r - ts1r; Fi[5] = ts0i - ts1i;
    Fr[3] = td0r + td1i; Fi[3] = td0i - td1r;
    Fr[7] = td0r - td1i; Fi[7] = td0i + td1r;
}

// Load 8x8 patch (scaled by 1/8 for ortho norm) and run stage-1 row FFTs.
__device__ __forceinline__ void stage1(const float* __restrict__ src, long base,
                                       float v[64]) {
    #pragma unroll
    for (int m = 0; m < 8; ++m) {
        const float4* p = reinterpret_cast<const float4*>(src + base + (long)m * 512);
        float4 a = p[0];
        float4 b = p[1];
        float r[8] = {a.x * 0.125f, a.y * 0.125f, a.z * 0.125f, a.w * 0.125f,
                      b.x * 0.125f, b.y * 0.125f, b.z * 0.125f, b.w * 0.125f};
        rfft8(r, &v[m * 8]);
    }
}

// Two lanes per patch: lanes 0..31 of each wave process the INPUT patch,
// lanes 32..63 the TARGET patch of the same 32 patch ids. Features are
// exchanged via __shfl_xor(.,32) as soon as they are produced, so no
// feature array stays live (peak ~a[64]+temps). Both halves accumulate the
// identical squared diff -> final scale carries a 0.5.
__global__ __launch_bounds__(256) void patchfft_loss_kernel(
        const float* __restrict__ in, const float* __restrict__ tgt,
        float* __restrict__ out) {
    int tid  = blockIdx.x * 256 + threadIdx.x;   // 0..393215 (2 threads per patch)
    int lane = threadIdx.x & 63;
    int sub  = lane & 31;
    int half = lane >> 5;                        // 0 = input, 1 = target
    int pidx = (tid >> 6) * 32 + sub;            // patch id 0..196607
    int pw = pidx & 63;
    int ph = (pidx >> 6) & 63;
    int bc = pidx >> 12;                         // fused batch*channel (0..47)
    long base = (long)bc * 262144 + ph * 4096 + pw * 8;
    const float* __restrict__ src = half ? tgt : in;

    float a[64];
    stage1(src, base, a);

    float acc1 = 0.0f, acc2 = 0.0f;

    // Columns l=0 (j=0) and l=4 (j=1): real sequences, packed rfft8 output.
    // o[0]=F(0,l) w1, o[1]=F(4,l) w1, o[2..7]=F(1..3,l) re/im w2.
    #pragma unroll
    for (int j = 0; j < 2; ++j) {
        float c[8], o[8];
        #pragma unroll
        for (int m = 0; m < 8; ++m) c[m] = a[m * 8 + j];
        rfft8(c, o);
        #pragma unroll
        for (int k = 0; k < 8; ++k) {
            float f = g2f(o[k]);
            float d = f - __shfl_xor(f, 32, 64);
            if (k < 2) acc1 += d * d;
            else       acc2 += d * d;
        }
    }

    // Columns l=1..3: complex column FFTs, all weight 2.
    #pragma unroll
    for (int l = 0; l < 3; ++l) {
        float cr[8], ci[8], Fr[8], Fi[8];
        #pragma unroll
        for (int m = 0; m < 8; ++m) {
            cr[m] = a[m * 8 + 2 + 2 * l];
            ci[m] = a[m * 8 + 3 + 2 * l];
        }
        cfft8(cr, ci, Fr, Fi);
        #pragma unroll
        for (int k = 0; k < 8; ++k) {
            float fr = g2f(Fr[k]);
            float fi = g2f(Fi[k]);
            float dr = fr - __shfl_xor(fr, 32, 64);
            float di = fi - __shfl_xor(fi, 32, 64);
            acc2 += dr * dr + di * di;
        }
    }

    float loss = acc1 + 2.0f * acc2;

    // wave (64-lane) shuffle reduce, then block reduce, then one atomic/block
    #pragma unroll
    for (int off = 32; off > 0; off >>= 1) loss += __shfl_down(loss, off, 64);
    __shared__ float wsum[4];
    int wid = threadIdx.x >> 6;
    if (lane == 0) wsum[wid] = loss;
    __syncthreads();
    if (threadIdx.x == 0) {
        // 0.5 (both halves accumulate) * ln2^2 (log2-domain feats) / mean-count
        constexpr float SCALE =
            (float)(0.5 * 0.48045301391820142467 / 12582912.0);
        float s = wsum[0] + wsum[1] + wsum[2] + wsum[3];
        atomicAdd(out, s * SCALE);
    }
}

extern "C" void kernel_launch(void* const* d_in, const int* in_sizes, int n_in,
                              void* d_out, int out_size, void* d_ws, size_t ws_size,
                              hipStream_t stream) {
    const float* in  = (const float*)d_in[0];
    const float* tgt = (const float*)d_in[1];
    float* out = (float*)d_out;
    (void)in_sizes; (void)n_in; (void)d_ws; (void)ws_size; (void)out_size;

    hipMemsetAsync(out, 0, sizeof(float), stream);   // d_out is poisoned 0xAA pre-launch
    // 196608 patches, two threads each (input lane / target lane)
    patchfft_loss_kernel<<<1536, 256, 0, stream>>>(in, tgt, out);
}

// Round 2
// 121.565 us; speedup vs baseline: 1.0147x; 1.0147x over previous
//
#include <hip/hip_runtime.h>

#define SQ1_2 0.70710678118654752440f

// 2-wide packed float for pairing independent FFT instances (SLP -> v_pk_*_f32).
struct v2 { float x, y; };
__device__ __forceinline__ v2 mk2(float a, float b) { v2 r; r.x = a; r.y = b; return r; }
__device__ __forceinline__ v2 operator+(v2 a, v2 b) { return mk2(a.x + b.x, a.y + b.y); }
__device__ __forceinline__ v2 operator-(v2 a, v2 b) { return mk2(a.x - b.x, a.y - b.y); }
__device__ __forceinline__ v2 operator-(v2 a)       { return mk2(-a.x, -a.y); }
__device__ __forceinline__ v2 operator*(float s, v2 a) { return mk2(s * a.x, s * a.y); }

// Feature in log2 domain: g2(x) = sign(x)*log2(1+|x|); ln2^2 folded into SCALE.
__device__ __forceinline__ float g2f(float x) {
    return copysignf(__log2f(1.0f + fabsf(x)), x);
}

// Real 8-point DFT, templated (T = float or v2 for two packed instances).
// Packed output: o[0]=F0, o[1]=F4, o[2..3]=F1(re,im), o[4..5]=F2, o[6..7]=F3.
template <typename T>
__device__ __forceinline__ void rfft8t(const T r[8], T o[8]) {
    T s0 = r[0] + r[4], d0 = r[0] - r[4];
    T s1 = r[1] + r[5], d1 = r[1] - r[5];
    T s2 = r[2] + r[6], d2 = r[2] - r[6];
    T s3 = r[3] + r[7], d3 = r[3] - r[7];
    T ss02 = s0 + s2, sd02 = s0 - s2;
    T ss13 = s1 + s3, sd13 = s1 - s3;
    T t1 = SQ1_2 * (d1 - d3);
    T t2 = SQ1_2 * (d1 + d3);
    o[0] = ss02 + ss13;       // F0
    o[1] = ss02 - ss13;       // F4
    o[2] = d0 + t1;           // F1r
    o[3] = -(d2 + t2);        // F1i
    o[4] = sd02;              // F2r
    o[5] = -sd13;             // F2i
    o[6] = d0 - t1;           // F3r
    o[7] = d2 - t2;           // F3i
}

// Complex 8-point DFT, templated (v2 = two independent complex FFTs packed).
template <typename T>
__device__ __forceinline__ void cfft8t(const T xr[8], const T xi[8],
                                       T Fr[8], T Fi[8]) {
    T s0r = xr[0] + xr[4], s0i = xi[0] + xi[4], d0r = xr[0] - xr[4], d0i = xi[0] - xi[4];
    T s1r = xr[1] + xr[5], s1i = xi[1] + xi[5], d1r = xr[1] - xr[5], d1i = xi[1] - xi[5];
    T s2r = xr[2] + xr[6], s2i = xi[2] + xi[6], d2r = xr[2] - xr[6], d2i = xi[2] - xi[6];
    T s3r = xr[3] + xr[7], s3i = xi[3] + xi[7], d3r = xr[3] - xr[7], d3i = xi[3] - xi[7];
    // even half: DFT4 of s
    T ss0r = s0r + s2r, ss0i = s0i + s2i, sd0r = s0r - s2r, sd0i = s0i - s2i;
    T ss1r = s1r + s3r, ss1i = s1i + s3i, sd1r = s1r - s3r, sd1i = s1i - s3i;
    Fr[0] = ss0r + ss1r; Fi[0] = ss0i + ss1i;
    Fr[4] = ss0r - ss1r; Fi[4] = ss0i - ss1i;
    Fr[2] = sd0r + sd1i; Fi[2] = sd0i - sd1r;   // sd0 - i*sd1
    Fr[6] = sd0r - sd1i; Fi[6] = sd0i + sd1r;   // sd0 + i*sd1
    // odd half: twiddle then DFT4
    T t1r = SQ1_2 * (d1r + d1i), t1i = SQ1_2 * (d1i - d1r);   // d1 * e^{-i pi/4}
    T t2r = d2i,                 t2i = -d2r;                  // d2 * (-i)
    T t3r = SQ1_2 * (d3i - d3r), t3i = -(SQ1_2 * (d3r + d3i)); // d3 * e^{-i 3pi/4}
    T ts0r = d0r + t2r, ts0i = d0i + t2i, td0r = d0r - t2r, td0i = d0i - t2i;
    T ts1r = t1r + t3r, ts1i = t1i + t3i, td1r = t1r - t3r, td1i = t1i - t3i;
    Fr[1] = ts0r + ts1r; Fi[1] = ts0i + ts1i;
    Fr[5] = ts0r - ts1r; Fi[5] = ts0i - ts1i;
    Fr[3] = td0r + td1i; Fi[3] = td0i - td1r;
    Fr[7] = td0r - td1i; Fi[7] = td0i + td1r;
}

// Two lanes per patch: lanes 0..31 of each wave = INPUT patch, lanes 32..63 =
// TARGET patch of the same 32 patch ids. Feature diffs via __shfl_xor(.,32).
// All 16 float4 loads are issued BEFORE any FFT so each wave keeps 16 loads
// in flight (latency hiding), instead of 8 serialized {load->FFT} phases.
__global__ __launch_bounds__(256) void patchfft_loss_kernel(
        const float* __restrict__ in, const float* __restrict__ tgt,
        float* __restrict__ out) {
    int tid  = blockIdx.x * 256 + threadIdx.x;   // 0..393215 (2 threads per patch)
    int lane = threadIdx.x & 63;
    int sub  = lane & 31;
    int half = lane >> 5;                        // 0 = input, 1 = target
    int pidx = (tid >> 6) * 32 + sub;            // patch id 0..196607
    int pw = pidx & 63;
    int ph = (pidx >> 6) & 63;
    int bc = pidx >> 12;                         // fused batch*channel (0..47)
    int base = bc * 262144 + ph * 4096 + pw * 8; // < 2^24, int ok
    const float* __restrict__ src = half ? tgt : in;

    // ---- issue all loads up front (16 outstanding float4 loads per lane) ----
    float4 raw[16];
    #pragma unroll
    for (int m = 0; m < 8; ++m) {
        const float4* p = reinterpret_cast<const float4*>(src + base + m * 512);
        raw[2 * m]     = p[0];
        raw[2 * m + 1] = p[1];
    }

    // ---- stage 1: row FFTs, two rows packed per rfft8 (v2) ----
    float a[64];
    #pragma unroll
    for (int mp = 0; mp < 4; ++mp) {
        float4 a0 = raw[4 * mp + 0], a1 = raw[4 * mp + 1];   // row 2*mp
        float4 b0 = raw[4 * mp + 2], b1 = raw[4 * mp + 3];   // row 2*mp+1
        v2 r[8] = {
            0.125f * mk2(a0.x, b0.x), 0.125f * mk2(a0.y, b0.y),
            0.125f * mk2(a0.z, b0.z), 0.125f * mk2(a0.w, b0.w),
            0.125f * mk2(a1.x, b1.x), 0.125f * mk2(a1.y, b1.y),
            0.125f * mk2(a1.z, b1.z), 0.125f * mk2(a1.w, b1.w)};
        v2 o[8];
        rfft8t(r, o);
        #pragma unroll
        for (int k = 0; k < 8; ++k) {
            a[(2 * mp) * 8 + k]     = o[k].x;
            a[(2 * mp + 1) * 8 + k] = o[k].y;
        }
    }

    float acc1 = 0.0f, acc2 = 0.0f;

    // ---- stage 2a: real columns j=0 (l=0) and j=1 (l=4), packed in one rfft8 ----
    {
        v2 c[8], o[8];
        #pragma unroll
        for (int m = 0; m < 8; ++m) c[m] = mk2(a[m * 8 + 0], a[m * 8 + 1]);
        rfft8t(c, o);
        #pragma unroll
        for (int k = 0; k < 8; ++k) {
            float f0 = g2f(o[k].x);
            float f1 = g2f(o[k].y);
            float d0 = f0 - __shfl_xor(f0, 32, 64);
            float d1 = f1 - __shfl_xor(f1, 32, 64);
            if (k < 2) acc1 += d0 * d0 + d1 * d1;   // F0/F4 bins, weight 1
            else       acc2 += d0 * d0 + d1 * d1;   // weight 2
        }
    }

    // ---- stage 2b: complex columns l=1,2 packed in one cfft8 ----
    {
        v2 cr[8], ci[8], Fr[8], Fi[8];
        #pragma unroll
        for (int m = 0; m < 8; ++m) {
            cr[m] = mk2(a[m * 8 + 2], a[m * 8 + 4]);
            ci[m] = mk2(a[m * 8 + 3], a[m * 8 + 5]);
        }
        cfft8t(cr, ci, Fr, Fi);
        #pragma unroll
        for (int k = 0; k < 8; ++k) {
            float fr0 = g2f(Fr[k].x), fi0 = g2f(Fi[k].x);
            float fr1 = g2f(Fr[k].y), fi1 = g2f(Fi[k].y);
            float dr0 = fr0 - __shfl_xor(fr0, 32, 64);
            float di0 = fi0 - __shfl_xor(fi0, 32, 64);
            float dr1 = fr1 - __shfl_xor(fr1, 32, 64);
            float di1 = fi1 - __shfl_xor(fi1, 32, 64);
            acc2 += dr0 * dr0 + di0 * di0 + dr1 * dr1 + di1 * di1;
        }
    }

    // ---- stage 2c: complex column l=3, scalar ----
    {
        float cr[8], ci[8], Fr[8], Fi[8];
        #pragma unroll
        for (int m = 0; m < 8; ++m) {
            cr[m] = a[m * 8 + 6];
            ci[m] = a[m * 8 + 7];
        }
        cfft8t(cr, ci, Fr, Fi);
        #pragma unroll
        for (int k = 0; k < 8; ++k) {
            float fr = g2f(Fr[k]), fi = g2f(Fi[k]);
            float dr = fr - __shfl_xor(fr, 32, 64);
            float di = fi - __shfl_xor(fi, 32, 64);
            acc2 += dr * dr + di * di;
        }
    }

    float loss = acc1 + 2.0f * acc2;

    // wave (64-lane) shuffle reduce, then block reduce, then one atomic/block
    #pragma unroll
    for (int off = 32; off > 0; off >>= 1) loss += __shfl_down(loss, off, 64);
    __shared__ float wsum[4];
    int wid = threadIdx.x >> 6;
    if (lane == 0) wsum[wid] = loss;
    __syncthreads();
    if (threadIdx.x == 0) {
        // 0.5 (both halves accumulate) * ln2^2 (log2-domain feats) / mean-count
        constexpr float SCALE =
            (float)(0.5 * 0.48045301391820142467 / 12582912.0);
        float s = wsum[0] + wsum[1] + wsum[2] + wsum[3];
        atomicAdd(out, s * SCALE);
    }
}

extern "C" void kernel_launch(void* const* d_in, const int* in_sizes, int n_in,
                              void* d_out, int out_size, void* d_ws, size_t ws_size,
                              hipStream_t stream) {
    const float* in  = (const float*)d_in[0];
    const float* tgt = (const float*)d_in[1];
    float* out = (float*)d_out;
    (void)in_sizes; (void)n_in; (void)d_ws; (void)ws_size; (void)out_size;

    hipMemsetAsync(out, 0, sizeof(float), stream);   // d_out is poisoned 0xAA pre-launch
    // 196608 patches, two threads each (input lane / target lane)
    patchfft_loss_kernel<<<1536, 256, 0, stream>>>(in, tgt, out);
}